// Round 10
// baseline (2103.950 us; speedup 1.0000x reference)
//
#include <hip/hip_runtime.h>

#define D 16
#define EFD 8
#define NREP 64       // BN-stats replica buffers
#define TSTRIDE 272   // Tt row stride
#define NB 1024       // persistent grid: 4 blocks/CU x 256 CUs (co-resident guaranteed)
#define NT 256

// ---------------- init: zero cnt arrays, BN stats, barrier state ----------------

__global__ void k_init(int* cnt2, int n2, float* st, int ns, int* bar) {
    int i = blockIdx.x * NT + threadIdx.x;
    if (i < n2) cnt2[i] = 0;
    if (i < ns) st[i] = 0.f;
    if (i < 4) bar[i] = 0;
}

// ---------------- device-scope grid barrier (all NB blocks co-resident) ----------------

__device__ __forceinline__ void gbar(int* cnt, int* gen) {
    __syncthreads();
    if (threadIdx.x == 0) {
        int g = __hip_atomic_load(gen, __ATOMIC_RELAXED, __HIP_MEMORY_SCOPE_AGENT);
        int p = __hip_atomic_fetch_add(cnt, 1, __ATOMIC_ACQ_REL, __HIP_MEMORY_SCOPE_AGENT);
        if (p == NB - 1) {
            __hip_atomic_store(cnt, 0, __ATOMIC_RELAXED, __HIP_MEMORY_SCOPE_AGENT);
            __hip_atomic_fetch_add(gen, 1, __ATOMIC_ACQ_REL, __HIP_MEMORY_SCOPE_AGENT);
        } else {
            while (__hip_atomic_load(gen, __ATOMIC_ACQUIRE, __HIP_MEMORY_SCOPE_AGENT) == g)
                __builtin_amdgcn_s_sleep(2);
        }
    }
    __syncthreads();
}

// ---------------- persistent mega-kernel: sort + edge MLP + 3 GNN layers ----------------

__global__ __launch_bounds__(256, 4)
void k_mega(const int* __restrict__ src, const int* __restrict__ dst,
            int* __restrict__ rankS, int* __restrict__ rankD,
            int* __restrict__ cnt2, int* __restrict__ offs2, int* __restrict__ bsum2,
            const float* __restrict__ ea, const float* __restrict__ ew1,
            const float* __restrict__ eb1, float* __restrict__ hE, int* __restrict__ permInv,
            const float* __restrict__ x, const float* __restrict__ ew2,
            const float* __restrict__ eb2, const float* __restrict__ gam,
            const float* __restrict__ bet, const float* __restrict__ root,
            const float* __restrict__ cb, float* __restrict__ msg,
            float* __restrict__ bufA, float* __restrict__ tmp,
            float* __restrict__ statsR3, int* __restrict__ bar,
            int n, int E_, int nChunk) {
    __shared__ __align__(16) float smem[4672];   // 18.7 KB union across phases
    int* smemI = (int*)smem;
    int tid = threadIdx.x;
    int* offsS = offs2;
    int* offsD = offs2 + (n + 1);

    // ---- P1: rank (1 atomic per edge per side; cnt2 becomes histogram) ----
    for (int e = blockIdx.x * NT + tid; e < E_; e += NB * NT) {
        rankS[e] = atomicAdd(&cnt2[src[e]], 1);
        rankD[e] = atomicAdd(&cnt2[n + dst[e]], 1);
    }
    gbar(bar, bar + 1);

    // ---- P2: chunk scans (1024 elems/chunk, 4/thread) ----
    for (int c = blockIdx.x; c < 2 * nChunk; c += NB) {
        int half = (c >= nChunk) ? 1 : 0;
        int blk = c - half * nChunk;
        const int* cc = cnt2 + (size_t)half * n;
        int* of = offs2 + (size_t)half * (n + 1);
        int base = blk * 1024 + tid * 4;
        int v0 = (base + 0 < n) ? cc[base + 0] : 0;
        int v1 = (base + 1 < n) ? cc[base + 1] : 0;
        int v2 = (base + 2 < n) ? cc[base + 2] : 0;
        int v3 = (base + 3 < n) ? cc[base + 3] : 0;
        int s1 = v0 + v1, s2 = s1 + v2, s3 = s2 + v3;
        smemI[tid] = s3;
        __syncthreads();
        for (int d = 1; d < 256; d <<= 1) {
            int t2 = (tid >= d) ? smemI[tid - d] : 0;
            __syncthreads();
            smemI[tid] += t2;
            __syncthreads();
        }
        int excl = smemI[tid] - s3;
        if (base + 0 < n) of[base + 0] = excl;
        if (base + 1 < n) of[base + 1] = excl + v0;
        if (base + 2 < n) of[base + 2] = excl + s1;
        if (base + 3 < n) of[base + 3] = excl + s2;
        if (tid == 255) bsum2[half * 64 + blk] = smemI[255];
        __syncthreads();
    }
    gbar(bar, bar + 1);

    // ---- P3: add chunk prefixes (redundant 64-entry scan per block) ----
    for (int c = blockIdx.x; c < 2 * nChunk; c += NB) {
        int half = (c >= nChunk) ? 1 : 0;
        int blk = c - half * nChunk;
        int* of = offs2 + (size_t)half * (n + 1);
        if (tid < 64) smemI[tid] = (tid < nChunk) ? bsum2[half * 64 + tid] : 0;
        __syncthreads();
        for (int d = 1; d < 64; d <<= 1) {
            int t2 = 0;
            if (tid < 64 && tid >= d) t2 = smemI[tid - d];
            __syncthreads();
            if (tid < 64) smemI[tid] += t2;
            __syncthreads();
        }
        int pre = (blk == 0) ? 0 : smemI[blk - 1];
        int i = blk * 1024 + tid * 4;
#pragma unroll
        for (int k = 0; k < 4; k++)
            if (i + k < n) of[i + k] += pre;
        if (blk == 0 && tid == 0) of[n] = E_;
        __syncthreads();
    }
    gbar(bar, bar + 1);

    // ---- P4: place + edge MLP + permInv (no atomics) ----
    {
        if (tid < EFD * D) smem[tid] = ew1[tid];
        if (tid < D) smem[128 + tid] = eb1[tid];
        __syncthreads();
        for (int e = blockIdx.x * NT + tid; e < E_; e += NB * NT) {
            int p = offsS[src[e]] + rankS[e];
            int q = offsD[dst[e]] + rankD[e];
            permInv[p] = q;
            const float4* a4 = (const float4*)(ea + (size_t)e * EFD);
            float4 x0 = a4[0], x1 = a4[1];
            float out[D];
#pragma unroll
            for (int o = 0; o < D; o++) {
                float u0 = x0.x * smem[0 * D + o] + x0.y * smem[1 * D + o]
                         + x0.z * smem[2 * D + o] + x0.w * smem[3 * D + o];
                float u1 = x1.x * smem[4 * D + o] + x1.y * smem[5 * D + o]
                         + x1.z * smem[6 * D + o] + x1.w * smem[7 * D + o];
                out[o] = tanhf(smem[128 + o] + u0 + u1);
            }
            float4* h4 = (float4*)(hE + (size_t)p * D);
#pragma unroll
            for (int v = 0; v < 4; v++)
                h4[v] = make_float4(out[v * 4], out[v * 4 + 1], out[v * 4 + 2], out[v * 4 + 3]);
        }
    }
    gbar(bar, bar + 1);

    // ---- P5..P10: 3 layers of [Tmsg phase, agg phase] ----
    int nTiles = (n + 15) >> 4;
    float fn = (float)n;
    float* hs = smem;              // 256 floats
    float* Tt = smem + 256;        // 16*272 floats
    float* sstats = smem + 4608;   // 32 floats

    for (int l = 0; l < 3; l++) {
        const float* hin = (l == 0) ? x : tmp;
        const float* hroot = (l == 0) ? x : bufA;
        const float* statsPrev = statsR3 + (size_t)(l - 1) * NREP * 32;
        float* statsCur = statsR3 + (size_t)l * NREP * 32;
        const float* gamL = gam + (size_t)(l - 1) * 16;
        const float* betL = bet + (size_t)(l - 1) * 16;
        int useBN = (l != 0);

        // ---- Tmsg ----
        for (int tile = blockIdx.x; tile < nTiles; tile += NB) {
            int j = tid >> 4, o = tid & 15;
            int base = tile * 16;
            int node = base + j;
            int p0 = 0, p1 = 0;
            if (node < n) { p0 = offsS[node]; p1 = offsS[node + 1]; }
            int qPre = 0;
            float4 a0, a1, a2, a3;
            if (p0 < p1) {          // first-edge prefetch overlaps the T phase
                qPre = permInv[p0];
                const float4* he4 = (const float4*)(hE + (size_t)p0 * D);
                a0 = he4[0]; a1 = he4[1]; a2 = he4[2]; a3 = he4[3];
            }
            float w16[16], b16[16];
#pragma unroll
            for (int i = 0; i < 16; i++) w16[i] = ew2[j * 256 + i * 16 + o];
#pragma unroll
            for (int i = 0; i < 16; i++) b16[i] = eb2[i * 16 + o];
            if (useBN && tid < 32) {
                float a = 0.f;
#pragma unroll 8
                for (int r = 0; r < NREP; r++) a += statsPrev[r * 32 + tid];
                sstats[tid] = a;
            }
            __syncthreads();
            {   // stage h rows (+ BN/tanh of prev layer)
                float hv = 0.f;
                if (node < n) {
                    float xin = hin[(size_t)node * D + o];
                    if (useBN) {
                        float mu = sstats[o] / fn;
                        float var = sstats[16 + o] / fn - mu * mu;
                        hv = tanhf((xin - mu) * rsqrtf(var + 1e-5f) * gamL[o] + betL[o]);
                        bufA[(size_t)node * D + o] = hv;
                    } else {
                        hv = xin;
                    }
                }
                hs[tid] = hv;
            }
            __syncthreads();
            {   // T tile: broadcast b128 hs reads + register FMAs (4-way trees)
                const float4* hs4 = (const float4*)hs;
#pragma unroll
                for (int nb = 0; nb < 16; nb++) {
                    float4 h0 = hs4[nb * 4 + 0], h1 = hs4[nb * 4 + 1];
                    float4 h2 = hs4[nb * 4 + 2], h3 = hs4[nb * 4 + 3];
                    float q0 = h0.x * w16[0]  + h0.y * w16[1]  + h0.z * w16[2]  + h0.w * w16[3];
                    float q1 = h1.x * w16[4]  + h1.y * w16[5]  + h1.z * w16[6]  + h1.w * w16[7];
                    float q2 = h2.x * w16[8]  + h2.y * w16[9]  + h2.z * w16[10] + h2.w * w16[11];
                    float q3 = h3.x * w16[12] + h3.y * w16[13] + h3.z * w16[14] + h3.w * w16[15];
                    Tt[nb * TSTRIDE + tid] = (q0 + q1) + (q2 + q3);
                }
                float4 h0 = hs4[j * 4 + 0], h1 = hs4[j * 4 + 1];
                float4 h2 = hs4[j * 4 + 2], h3 = hs4[j * 4 + 3];
                float q0 = h0.x * b16[0]  + h0.y * b16[1]  + h0.z * b16[2]  + h0.w * b16[3];
                float q1 = h1.x * b16[4]  + h1.y * b16[5]  + h1.z * b16[6]  + h1.w * b16[7];
                float q2 = h2.x * b16[8]  + h2.y * b16[9]  + h2.z * b16[10] + h2.w * b16[11];
                float q3 = h3.x * b16[12] + h3.y * b16[13] + h3.z * b16[14] + h3.w * b16[15];
                Tt[j * TSTRIDE + 256 + o] = (q0 + q1) + (q2 + q3);
            }
            __syncthreads();
            if (node < n) {   // messages: 1-deep pipelined, 4-way FMA trees
                float tr[16];
#pragma unroll
                for (int j2 = 0; j2 < 16; j2++) tr[j2] = Tt[j * TSTRIDE + j2 * 16 + o];
                float tb = Tt[j * TSTRIDE + 256 + o];
                int q = qPre;
                for (int p = p0; p < p1; p++) {
                    float4 b0 = a0, b1 = a1, b2 = a2, b3 = a3;
                    int qc = q;
                    if (p + 1 < p1) {
                        q = permInv[p + 1];
                        const float4* n4 = (const float4*)(hE + (size_t)(p + 1) * D);
                        a0 = n4[0]; a1 = n4[1]; a2 = n4[2]; a3 = n4[3];
                    }
                    float s0 = b0.x * tr[0]  + b0.y * tr[1]  + b0.z * tr[2]  + b0.w * tr[3];
                    float s1 = b1.x * tr[4]  + b1.y * tr[5]  + b1.z * tr[6]  + b1.w * tr[7];
                    float s2 = b2.x * tr[8]  + b2.y * tr[9]  + b2.z * tr[10] + b2.w * tr[11];
                    float s3 = b3.x * tr[12] + b3.y * tr[13] + b3.z * tr[14] + b3.w * tr[15];
                    msg[(size_t)qc * D + o] = tb + ((s0 + s1) + (s2 + s3));
                }
            }
        }
        gbar(bar, bar + 1);

        // ---- agg ----
        {
            float* rootS = smem;           // 256
            float* red = smem + 256;       // 256
            float* red2 = smem + 512;      // 256
            const float* root_l = root + (size_t)l * 256;
            const float* cbias = cb + (size_t)l * 16;
            for (int tile = blockIdx.x; tile < nTiles; tile += NB) {
                rootS[tid] = root_l[tid];
                __syncthreads();
                int slot = tid >> 4, o = tid & 15;
                int node = tile * 16 + slot;
                float acc = 0.f;
                if (node < n) {
                    int p0 = offsD[node], p1 = offsD[node + 1];
                    float sum = 0.f;
                    int p = p0;
                    for (; p + 4 <= p1; p += 4) {
                        float a0 = msg[(size_t)(p + 0) * D + o];
                        float a1 = msg[(size_t)(p + 1) * D + o];
                        float a2 = msg[(size_t)(p + 2) * D + o];
                        float a3 = msg[(size_t)(p + 3) * D + o];
                        sum += (a0 + a1) + (a2 + a3);
                    }
                    for (; p < p1; p++) sum += msg[(size_t)p * D + o];
                    float deg = (float)((p1 - p0) > 1 ? (p1 - p0) : 1);
                    const float* hr = hroot + (size_t)node * D;
                    float r0 = hr[0] * rootS[0 * D + o]  + hr[1] * rootS[1 * D + o]
                             + hr[2] * rootS[2 * D + o]  + hr[3] * rootS[3 * D + o];
                    float r1 = hr[4] * rootS[4 * D + o]  + hr[5] * rootS[5 * D + o]
                             + hr[6] * rootS[6 * D + o]  + hr[7] * rootS[7 * D + o];
                    float r2 = hr[8] * rootS[8 * D + o]  + hr[9] * rootS[9 * D + o]
                             + hr[10] * rootS[10 * D + o] + hr[11] * rootS[11 * D + o];
                    float r3 = hr[12] * rootS[12 * D + o] + hr[13] * rootS[13 * D + o]
                             + hr[14] * rootS[14 * D + o] + hr[15] * rootS[15 * D + o];
                    acc = sum / deg + cbias[o] + ((r0 + r1) + (r2 + r3));
                    tmp[(size_t)node * D + o] = acc;
                }
                red[tid] = acc;
                red2[tid] = acc * acc;
                __syncthreads();
                for (int off = 128; off >= 16; off >>= 1) {
                    if (tid < off) {
                        red[tid] += red[tid + off];
                        red2[tid] += red2[tid + off];
                    }
                    __syncthreads();
                }
                if (tid < 32) {
                    float v = (tid < 16) ? red[tid] : red2[tid - 16];
                    atomicAdd(&statsCur[((unsigned)tile & (NREP - 1)) * 32 + tid], v);
                }
                __syncthreads();   // protect red/red2 before next tile
            }
        }
        if (l < 2) gbar(bar, bar + 1);
    }
}

// ---------------- fused readout: final BN+tanh + hidden write + pool + MLP + log_softmax ----------------

__global__ void k_readout(const float* __restrict__ hpre, const float* __restrict__ statsR,
                          const float* __restrict__ gamma, const float* __restrict__ beta,
                          const int* __restrict__ lengths,
                          const float* __restrict__ w1, const float* __restrict__ b1,
                          const float* __restrict__ w2, const float* __restrict__ b2,
                          float* __restrict__ outHidden, float* __restrict__ outPooled,
                          float* __restrict__ fcOut, float* __restrict__ lsmOut,
                          int Gc, int n) {
    __shared__ int sl[512];
    __shared__ float sstats[32];
    int tid = threadIdx.x;
    int g = blockIdx.x;
    if (tid < 32) {
        float a = 0.f;
#pragma unroll 8
        for (int r = 0; r < NREP; r++) a += statsR[r * 32 + tid];
        sstats[tid] = a;
    }
    int v = (tid < Gc) ? lengths[tid] : 0;
    sl[tid] = v;
    __syncthreads();
    for (int d = 1; d < 512; d <<= 1) {
        int t = (tid >= d) ? sl[tid - d] : 0;
        __syncthreads();
        sl[tid] += t;
        __syncthreads();
    }
    int n1 = sl[g];
    int n0 = n1 - lengths[g];
    float fn = (float)n;
    int slot = tid >> 4, o = tid & 15;
    float mu = sstats[o] / fn;
    float var = sstats[16 + o] / fn - mu * mu;
    float rstd = rsqrtf(var + 1e-5f);
    float gm = gamma[o], bt = beta[o];
    float s = 0.f, mx = -3.402823466e38f, mn = 3.402823466e38f;
    for (int nd = n0 + slot; nd < n1; nd += 32) {
        float xin = hpre[(size_t)nd * D + o];
        float x = tanhf((xin - mu) * rstd * gm + bt);
        outHidden[(size_t)nd * D + o] = x;
        s += x;
        mx = fmaxf(mx, x);
        mn = fminf(mn, x);
    }
    __shared__ float rs[512], rmx[512], rmn[512];
    rs[tid] = s; rmx[tid] = mx; rmn[tid] = mn;
    __syncthreads();
    for (int off = 256; off >= 16; off >>= 1) {
        if (tid < off) {
            rs[tid] += rs[tid + off];
            rmx[tid] = fmaxf(rmx[tid], rmx[tid + off]);
            rmn[tid] = fminf(rmn[tid], rmn[tid + off]);
        }
        __syncthreads();
    }
    __shared__ float p64[64], t16[16], f10[10];
    __shared__ float mred, lred;
    if (tid < 16) {
        float cnt = fmaxf((float)(n1 - n0), 1.f);
        float sum = rs[tid];
        float* row = outPooled + (size_t)g * 64;
        float mean = sum / cnt;
        p64[tid] = mean;          row[tid] = mean;
        p64[16 + tid] = rmx[tid]; row[16 + tid] = rmx[tid];
        p64[32 + tid] = rmn[tid]; row[32 + tid] = rmn[tid];
        p64[48 + tid] = sum;      row[48 + tid] = sum;
    }
    __syncthreads();
    if (tid < 16) {
        float a = b1[tid];
        for (int k = 0; k < 64; k++) a += p64[k] * w1[k * 16 + tid];
        t16[tid] = tanhf(a);
    }
    __syncthreads();
    if (tid < 10) {
        float a = b2[tid];
        for (int oo = 0; oo < 16; oo++) a += t16[oo] * w2[oo * 10 + tid];
        f10[tid] = a;
        fcOut[(size_t)g * 10 + tid] = a;
    }
    __syncthreads();
    if (tid == 0) {
        float m = f10[0];
        for (int c = 1; c < 10; c++) m = fmaxf(m, f10[c]);
        float se = 0.f;
        for (int c = 0; c < 10; c++) se += expf(f10[c] - m);
        mred = m;
        lred = logf(se);
    }
    __syncthreads();
    if (tid < 10)
        lsmOut[(size_t)g * 10 + tid] = f10[tid] - mred - lred;
}

// ---------------- host ----------------

extern "C" void kernel_launch(void* const* d_in, const int* in_sizes, int n_in,
                              void* d_out, int out_size, void* d_ws, size_t ws_size,
                              hipStream_t stream) {
    const float* x    = (const float*)d_in[0];
    const float* ea   = (const float*)d_in[1];
    const float* ew1  = (const float*)d_in[2];
    const float* eb1  = (const float*)d_in[3];
    const float* ew2  = (const float*)d_in[4];
    const float* eb2  = (const float*)d_in[5];
    const float* root = (const float*)d_in[6];
    const float* cb   = (const float*)d_in[7];
    const float* gam  = (const float*)d_in[8];
    const float* bet  = (const float*)d_in[9];
    const float* f1w  = (const float*)d_in[10];
    const float* f1b  = (const float*)d_in[11];
    const float* f2w  = (const float*)d_in[12];
    const float* f2b  = (const float*)d_in[13];
    const int* eidx   = (const int*)d_in[14];
    const int* lens   = (const int*)d_in[15];

    int N  = in_sizes[0] / D;
    int E_ = in_sizes[1] / EFD;
    int Gc = in_sizes[15];
    const int* srcIdx = eidx;
    const int* dstIdx = eidx + E_;

    float* outHidden = (float*)d_out;
    float* outPooled = outHidden + (size_t)N * D;
    float* outFc     = outPooled + (size_t)Gc * 4 * D;
    float* outLsm    = outFc + (size_t)Gc * 10;

    char* wsp = (char*)d_ws;
    size_t off = 0;
    auto alloc = [&](size_t bytes) -> void* {
        void* p = wsp + off;
        off = (off + bytes + 255) & ~(size_t)255;
        return p;
    };
    int*   bar     = (int*)alloc(16);
    int*   cnt2    = (int*)alloc((size_t)2 * N * 4);
    int*   offs2   = (int*)alloc((size_t)2 * (N + 1) * 4);
    int*   bsum2   = (int*)alloc(128 * 4);
    int*   rankS   = (int*)alloc((size_t)E_ * 4);
    int*   rankD   = (int*)alloc((size_t)E_ * 4);
    int*   permInv = (int*)alloc((size_t)E_ * 4);
    float* hE      = (float*)alloc((size_t)E_ * D * 4);
    float* msg     = (float*)alloc((size_t)E_ * D * 4);
    float* bufA    = (float*)alloc((size_t)N * D * 4);
    float* tmp     = (float*)alloc((size_t)N * D * 4);
    float* statsR3 = (float*)alloc((size_t)3 * NREP * 32 * 4);

    int nChunk = (N + 1023) / 1024;
    int nInit = (2 * N > 3 * NREP * 32) ? 2 * N : 3 * NREP * 32;

    k_init<<<(nInit + NT - 1) / NT, NT, 0, stream>>>(cnt2, 2 * N, statsR3, 3 * NREP * 32, bar);
    k_mega<<<NB, NT, 0, stream>>>(srcIdx, dstIdx, rankS, rankD, cnt2, offs2, bsum2,
                                  ea, ew1, eb1, hE, permInv, x, ew2, eb2, gam, bet,
                                  root, cb, msg, bufA, tmp, statsR3, bar, N, E_, nChunk);
    k_readout<<<Gc, 512, 0, stream>>>(tmp, statsR3 + (size_t)2 * NREP * 32,
                                      gam + 32, bet + 32, lens, f1w, f1b, f2w, f2b,
                                      outHidden, outPooled, outFc, outLsm, Gc, N);
}

// Round 11
// 291.475 us; speedup vs baseline: 7.2183x; 7.2183x over previous
//
#include <hip/hip_runtime.h>

#define D 16
#define EFD 8
#define NREP 64       // BN-stats replica buffers (breaks atomic same-line contention)
#define TSTRIDE 272   // Tt row: 256 T values + 16 bias; 272%32==16 -> benign aliasing

typedef unsigned short u16;
typedef unsigned int u32;

__device__ __forceinline__ u16 f2bf(float x) {          // round-to-nearest-even
    u32 u = __float_as_uint(x);
    u += 0x7fffu + ((u >> 16) & 1u);
    return (u16)(u >> 16);
}
__device__ __forceinline__ void unpack8(uint4 u, float* f) {
    f[0] = __uint_as_float(u.x << 16); f[1] = __uint_as_float(u.x & 0xffff0000u);
    f[2] = __uint_as_float(u.y << 16); f[3] = __uint_as_float(u.y & 0xffff0000u);
    f[4] = __uint_as_float(u.z << 16); f[5] = __uint_as_float(u.z & 0xffff0000u);
    f[6] = __uint_as_float(u.w << 16); f[7] = __uint_as_float(u.w & 0xffff0000u);
}

// ---------------- zero scratch (cnt arrays + all 3 BN stat slots) ----------------

__global__ void k_zero2(int* a, int na, float* b, int nb) {
    int i = blockIdx.x * 256 + threadIdx.x;
    if (i < na) a[i] = 0;
    if (i < nb) b[i] = 0.f;
}

// ---------------- rank: one atomic per edge per side; cnt becomes the histogram ----------------

__global__ void k_rank2(const int* __restrict__ src, const int* __restrict__ dst,
                        int* __restrict__ cntS, int* __restrict__ cntD,
                        int* __restrict__ rankS, int* __restrict__ rankD, int E_) {
    int e = blockIdx.x * 256 + threadIdx.x;
    if (e < E_) {
        rankS[e] = atomicAdd(&cntS[src[e]], 1);
        rankD[e] = atomicAdd(&cntD[dst[e]], 1);
    }
}

// ---------------- scans over cntS|cntD (both halves in one launch) ----------------

__global__ void k_scanA2(const int* __restrict__ cnt2, int* __restrict__ offs2,
                         int* __restrict__ bsum2, int n, int nScan) {
    __shared__ int s[1024];
    int half = blockIdx.x / nScan;
    int blk  = blockIdx.x % nScan;
    const int* c = cnt2 + (size_t)half * n;
    int* of = offs2 + (size_t)half * (n + 1);
    int* bs = bsum2 + half * 64;
    int i = blk * 1024 + threadIdx.x;
    int v = (i < n) ? c[i] : 0;
    s[threadIdx.x] = v;
    __syncthreads();
    for (int d = 1; d < 1024; d <<= 1) {
        int t = (threadIdx.x >= d) ? s[threadIdx.x - d] : 0;
        __syncthreads();
        s[threadIdx.x] += t;
        __syncthreads();
    }
    int incl = s[threadIdx.x];
    if (i < n) of[i] = incl - v;            // exclusive within chunk
    if (threadIdx.x == 1023) bs[blk] = incl;
}

// scanC with the 64-entry block-sum scan folded in (done redundantly per block)
__global__ void k_scanC2(int* __restrict__ offs2, const int* __restrict__ bsum2,
                         int n, int nScan, int total) {
    __shared__ int s[64];
    int half = blockIdx.x / nScan;
    int blk  = blockIdx.x % nScan;
    int* of = offs2 + (size_t)half * (n + 1);
    const int* bs = bsum2 + half * 64;
    if (threadIdx.x < 64) s[threadIdx.x] = (threadIdx.x < nScan) ? bs[threadIdx.x] : 0;
    __syncthreads();
    if (threadIdx.x < 64) {
        for (int d = 1; d < 64; d <<= 1) {
            int t = (threadIdx.x >= d) ? s[threadIdx.x - d] : 0;
            __syncthreads();
            s[threadIdx.x] += t;
            __syncthreads();
        }
    } else {
        for (int d = 1; d < 64; d <<= 1) { __syncthreads(); __syncthreads(); }
    }
    int base = (blk == 0) ? 0 : s[blk - 1];
    int i = blk * 1024 + threadIdx.x;
    if (i < n) of[i] += base;
    else if (i == n) of[n] = total;
}

// ---------------- fused place + edge-MLP + permInv: NO atomics; hE stored bf16 ----------------

__global__ void k_place_he(const int* __restrict__ src, const int* __restrict__ dst,
                           const int* __restrict__ rankS, const int* __restrict__ rankD,
                           const int* __restrict__ offsS, const int* __restrict__ offsD,
                           const float* __restrict__ ea, const float* __restrict__ w1,
                           const float* __restrict__ b1,
                           u16* __restrict__ hE, int* __restrict__ permInv, int E_) {
    __shared__ float w1s[EFD * D];
    __shared__ float b1s[D];
    if (threadIdx.x < EFD * D) w1s[threadIdx.x] = w1[threadIdx.x];
    if (threadIdx.x < D) b1s[threadIdx.x] = b1[threadIdx.x];
    __syncthreads();
    int e = blockIdx.x * 256 + threadIdx.x;
    if (e >= E_) return;
    int p = offsS[src[e]] + rankS[e];
    int q = offsD[dst[e]] + rankD[e];
    permInv[p] = q;
    const float4* a4 = (const float4*)(ea + (size_t)e * EFD);
    float4 x0 = a4[0], x1 = a4[1];
    u32 pk[8];
#pragma unroll
    for (int v = 0; v < 8; v++) {
        float o0, o1;
#pragma unroll
        for (int h = 0; h < 2; h++) {
            int o = 2 * v + h;
            float u0 = x0.x * w1s[0 * D + o] + x0.y * w1s[1 * D + o]
                     + x0.z * w1s[2 * D + o] + x0.w * w1s[3 * D + o];
            float u1 = x1.x * w1s[4 * D + o] + x1.y * w1s[5 * D + o]
                     + x1.z * w1s[6 * D + o] + x1.w * w1s[7 * D + o];
            float t = tanhf(b1s[o] + u0 + u1);
            if (h == 0) o0 = t; else o1 = t;
        }
        pk[v] = (u32)f2bf(o0) | ((u32)f2bf(o1) << 16);
    }
    uint4* h8 = (uint4*)(hE + (size_t)p * D);   // 32B row
    h8[0] = make_uint4(pk[0], pk[1], pk[2], pk[3]);
    h8[1] = make_uint4(pk[4], pk[5], pk[6], pk[7]);
}

// ---------------- per-layer FUSED: [BN+tanh prev] + T-tile + messages (pipelined, bf16 I/O) ----------------

__global__ void k_Tmsg(const float* __restrict__ hin, const float* __restrict__ statsPrev,
                       const float* __restrict__ gamma, const float* __restrict__ beta,
                       float* __restrict__ hout, const float* __restrict__ w2,
                       const float* __restrict__ b2, const u16* __restrict__ hE,
                       const int* __restrict__ offsS, const int* __restrict__ permInv,
                       u16* __restrict__ msg, int n, int useBN) {
    __shared__ float hs[16 * D];          // 16 nodes x 16 feat
    __shared__ float Tt[16 * TSTRIDE];    // [slot][j*16+o | 256+o]
    __shared__ float sstats[32];
    int tid = threadIdx.x;
    int j = tid >> 4, o = tid & 15;
    int base = blockIdx.x * 16;
    int node = base + j;                  // the node this thread will emit messages for
    float fn = (float)n;
    int p0 = 0, p1 = 0;
    if (node < n) { p0 = offsS[node]; p1 = offsS[node + 1]; }
    // first-edge prefetch (overlaps the T-phase FMAs)
    int qPre = 0;
    uint4 a0, a1;
    if (p0 < p1) {
        qPre = permInv[p0];
        const uint4* he8 = (const uint4*)(hE + (size_t)p0 * D);
        a0 = he8[0]; a1 = he8[1];
    }
    // per-thread weight columns in registers
    float w16[16], b16[16];
#pragma unroll
    for (int i = 0; i < 16; i++) w16[i] = w2[j * 256 + i * 16 + o];
#pragma unroll
    for (int i = 0; i < 16; i++) b16[i] = b2[i * 16 + o];
    if (useBN && tid < 32) {
        float a = 0.f;
#pragma unroll 8
        for (int r = 0; r < NREP; r++) a += statsPrev[r * 32 + tid];
        sstats[tid] = a;
    }
    __syncthreads();
    {   // stage h rows (apply BN+tanh of previous layer if needed)
        float hv = 0.f;
        if (node < n) {
            float xin = hin[(size_t)node * D + o];
            if (useBN) {
                float mu = sstats[o] / fn;
                float var = sstats[16 + o] / fn - mu * mu;
                hv = tanhf((xin - mu) * rsqrtf(var + 1e-5f) * gamma[o] + beta[o]);
                hout[(size_t)node * D + o] = hv;
            } else {
                hv = xin;
            }
        }
        hs[tid] = hv;   // hs[j*16 + o]
    }
    __syncthreads();
    {   // T-tile: broadcast b128 reads of hs + register FMAs (4-way trees)
        const float4* hs4 = (const float4*)hs;
#pragma unroll
        for (int nb = 0; nb < 16; nb++) {
            float4 h0 = hs4[nb * 4 + 0], h1 = hs4[nb * 4 + 1];
            float4 h2 = hs4[nb * 4 + 2], h3 = hs4[nb * 4 + 3];
            float q0 = h0.x * w16[0]  + h0.y * w16[1]  + h0.z * w16[2]  + h0.w * w16[3];
            float q1 = h1.x * w16[4]  + h1.y * w16[5]  + h1.z * w16[6]  + h1.w * w16[7];
            float q2 = h2.x * w16[8]  + h2.y * w16[9]  + h2.z * w16[10] + h2.w * w16[11];
            float q3 = h3.x * w16[12] + h3.y * w16[13] + h3.z * w16[14] + h3.w * w16[15];
            Tt[nb * TSTRIDE + tid] = (q0 + q1) + (q2 + q3);
        }
        float4 h0 = hs4[j * 4 + 0], h1 = hs4[j * 4 + 1];
        float4 h2 = hs4[j * 4 + 2], h3 = hs4[j * 4 + 3];
        float q0 = h0.x * b16[0]  + h0.y * b16[1]  + h0.z * b16[2]  + h0.w * b16[3];
        float q1 = h1.x * b16[4]  + h1.y * b16[5]  + h1.z * b16[6]  + h1.w * b16[7];
        float q2 = h2.x * b16[8]  + h2.y * b16[9]  + h2.z * b16[10] + h2.w * b16[11];
        float q3 = h3.x * b16[12] + h3.y * b16[13] + h3.z * b16[14] + h3.w * b16[15];
        Tt[j * TSTRIDE + 256 + o] = (q0 + q1) + (q2 + q3);
    }
    __syncthreads();
    if (node < n) {   // messages: 1-deep pipelined degree loop, bf16 in/out
        float tr[16];
#pragma unroll
        for (int j2 = 0; j2 < 16; j2++) tr[j2] = Tt[j * TSTRIDE + j2 * 16 + o];
        float tb = Tt[j * TSTRIDE + 256 + o];
        int q = qPre;
        for (int p = p0; p < p1; p++) {
            uint4 c0 = a0, c1 = a1;
            int qc = q;
            if (p + 1 < p1) {               // prefetch next edge before consuming current
                q = permInv[p + 1];
                const uint4* n8 = (const uint4*)(hE + (size_t)(p + 1) * D);
                a0 = n8[0]; a1 = n8[1];
            }
            float e[16];
            unpack8(c0, e); unpack8(c1, e + 8);
            float s0 = e[0]  * tr[0]  + e[1]  * tr[1]  + e[2]  * tr[2]  + e[3]  * tr[3];
            float s1 = e[4]  * tr[4]  + e[5]  * tr[5]  + e[6]  * tr[6]  + e[7]  * tr[7];
            float s2 = e[8]  * tr[8]  + e[9]  * tr[9]  + e[10] * tr[10] + e[11] * tr[11];
            float s3 = e[12] * tr[12] + e[13] * tr[13] + e[14] * tr[14] + e[15] * tr[15];
            msg[(size_t)qc * D + o] = f2bf(tb + ((s0 + s1) + (s2 + s3)));
        }
    }
}

// ---------------- per-layer: dst aggregation (sequential bf16 msg read) + root + bias + BN stats ----------------

__global__ void k_agg(const float* __restrict__ h, const u16* __restrict__ msg,
                      const int* __restrict__ offsD, const float* __restrict__ root_l,
                      const float* __restrict__ cbias, float* __restrict__ hpre,
                      float* __restrict__ statsR, int n) {
    __shared__ float rootS[D * D];
    __shared__ float red[256], red2[256];
    if (threadIdx.x < D * D) rootS[threadIdx.x] = root_l[threadIdx.x];
    __syncthreads();
    int slot = threadIdx.x >> 4, o = threadIdx.x & 15;
    int node = blockIdx.x * 16 + slot;
    float acc = 0.f;
    if (node < n) {
        int p0 = offsD[node], p1 = offsD[node + 1];
        float sum = 0.f;
        int p = p0;
        for (; p + 4 <= p1; p += 4) {           // unrolled: 4 independent loads in flight
            float a0 = __uint_as_float((u32)msg[(size_t)(p + 0) * D + o] << 16);
            float a1 = __uint_as_float((u32)msg[(size_t)(p + 1) * D + o] << 16);
            float a2 = __uint_as_float((u32)msg[(size_t)(p + 2) * D + o] << 16);
            float a3 = __uint_as_float((u32)msg[(size_t)(p + 3) * D + o] << 16);
            sum += (a0 + a1) + (a2 + a3);
        }
        for (; p < p1; p++) sum += __uint_as_float((u32)msg[(size_t)p * D + o] << 16);
        float deg = (float)((p1 - p0) > 1 ? (p1 - p0) : 1);
        const float* hr = h + (size_t)node * D;
        float r0 = hr[0]  * rootS[0 * D + o]  + hr[1]  * rootS[1 * D + o]
                 + hr[2]  * rootS[2 * D + o]  + hr[3]  * rootS[3 * D + o];
        float r1 = hr[4]  * rootS[4 * D + o]  + hr[5]  * rootS[5 * D + o]
                 + hr[6]  * rootS[6 * D + o]  + hr[7]  * rootS[7 * D + o];
        float r2 = hr[8]  * rootS[8 * D + o]  + hr[9]  * rootS[9 * D + o]
                 + hr[10] * rootS[10 * D + o] + hr[11] * rootS[11 * D + o];
        float r3 = hr[12] * rootS[12 * D + o] + hr[13] * rootS[13 * D + o]
                 + hr[14] * rootS[14 * D + o] + hr[15] * rootS[15 * D + o];
        acc = sum / deg + cbias[o] + ((r0 + r1) + (r2 + r3));
        hpre[(size_t)node * D + o] = acc;
    }
    red[threadIdx.x] = acc;
    red2[threadIdx.x] = acc * acc;
    __syncthreads();
    for (int off = 128; off >= 16; off >>= 1) {
        if (threadIdx.x < off) {
            red[threadIdx.x] += red[threadIdx.x + off];
            red2[threadIdx.x] += red2[threadIdx.x + off];
        }
        __syncthreads();
    }
    if (threadIdx.x < 32) {
        float v = (threadIdx.x < 16) ? red[threadIdx.x] : red2[threadIdx.x - 16];
        atomicAdd(&statsR[(blockIdx.x & (NREP - 1)) * 32 + threadIdx.x], v);
    }
}

// ---------------- fused readout: final BN+tanh + hidden write + pool + MLP + log_softmax ----------------

__global__ void k_readout(const float* __restrict__ hpre, const float* __restrict__ statsR,
                          const float* __restrict__ gamma, const float* __restrict__ beta,
                          const int* __restrict__ lengths,
                          const float* __restrict__ w1, const float* __restrict__ b1,
                          const float* __restrict__ w2, const float* __restrict__ b2,
                          float* __restrict__ outHidden, float* __restrict__ outPooled,
                          float* __restrict__ fcOut, float* __restrict__ lsmOut,
                          int Gc, int n) {
    __shared__ int sl[512];
    __shared__ float sstats[32];
    int tid = threadIdx.x;
    int g = blockIdx.x;
    if (tid < 32) {
        float a = 0.f;
#pragma unroll 8
        for (int r = 0; r < NREP; r++) a += statsR[r * 32 + tid];
        sstats[tid] = a;
    }
    int v = (tid < Gc) ? lengths[tid] : 0;
    sl[tid] = v;
    __syncthreads();
    for (int d = 1; d < 512; d <<= 1) {
        int t = (tid >= d) ? sl[tid - d] : 0;
        __syncthreads();
        sl[tid] += t;
        __syncthreads();
    }
    int n1 = sl[g];
    int n0 = n1 - lengths[g];
    float fn = (float)n;
    int slot = tid >> 4, o = tid & 15;
    float mu = sstats[o] / fn;
    float var = sstats[16 + o] / fn - mu * mu;
    float rstd = rsqrtf(var + 1e-5f);
    float gm = gamma[o], bt = beta[o];
    float s = 0.f, mx = -3.402823466e38f, mn = 3.402823466e38f;
    for (int nd = n0 + slot; nd < n1; nd += 32) {
        float xin = hpre[(size_t)nd * D + o];
        float x = tanhf((xin - mu) * rstd * gm + bt);
        outHidden[(size_t)nd * D + o] = x;
        s += x;
        mx = fmaxf(mx, x);
        mn = fminf(mn, x);
    }
    __shared__ float rs[512], rmx[512], rmn[512];
    rs[tid] = s; rmx[tid] = mx; rmn[tid] = mn;
    __syncthreads();
    for (int off = 256; off >= 16; off >>= 1) {
        if (tid < off) {
            rs[tid] += rs[tid + off];
            rmx[tid] = fmaxf(rmx[tid], rmx[tid + off]);
            rmn[tid] = fminf(rmn[tid], rmn[tid + off]);
        }
        __syncthreads();
    }
    __shared__ float p64[64], t16[16], f10[10];
    __shared__ float mred, lred;
    if (tid < 16) {
        float cnt = fmaxf((float)(n1 - n0), 1.f);
        float sum = rs[tid];
        float* row = outPooled + (size_t)g * 64;
        float mean = sum / cnt;
        p64[tid] = mean;          row[tid] = mean;
        p64[16 + tid] = rmx[tid]; row[16 + tid] = rmx[tid];
        p64[32 + tid] = rmn[tid]; row[32 + tid] = rmn[tid];
        p64[48 + tid] = sum;      row[48 + tid] = sum;
    }
    __syncthreads();
    if (tid < 16) {
        float a = b1[tid];
        for (int k = 0; k < 64; k++) a += p64[k] * w1[k * 16 + tid];
        t16[tid] = tanhf(a);
    }
    __syncthreads();
    if (tid < 10) {
        float a = b2[tid];
        for (int oo = 0; oo < 16; oo++) a += t16[oo] * w2[oo * 10 + tid];
        f10[tid] = a;
        fcOut[(size_t)g * 10 + tid] = a;
    }
    __syncthreads();
    if (tid == 0) {
        float m = f10[0];
        for (int c = 1; c < 10; c++) m = fmaxf(m, f10[c]);
        float se = 0.f;
        for (int c = 0; c < 10; c++) se += expf(f10[c] - m);
        mred = m;
        lred = logf(se);
    }
    __syncthreads();
    if (tid < 10)
        lsmOut[(size_t)g * 10 + tid] = f10[tid] - mred - lred;
}

// ---------------- host ----------------

extern "C" void kernel_launch(void* const* d_in, const int* in_sizes, int n_in,
                              void* d_out, int out_size, void* d_ws, size_t ws_size,
                              hipStream_t stream) {
    const float* x    = (const float*)d_in[0];
    const float* ea   = (const float*)d_in[1];
    const float* ew1  = (const float*)d_in[2];
    const float* eb1  = (const float*)d_in[3];
    const float* ew2  = (const float*)d_in[4];
    const float* eb2  = (const float*)d_in[5];
    const float* root = (const float*)d_in[6];
    const float* cb   = (const float*)d_in[7];
    const float* gam  = (const float*)d_in[8];
    const float* bet  = (const float*)d_in[9];
    const float* f1w  = (const float*)d_in[10];
    const float* f1b  = (const float*)d_in[11];
    const float* f2w  = (const float*)d_in[12];
    const float* f2b  = (const float*)d_in[13];
    const int* eidx   = (const int*)d_in[14];
    const int* lens   = (const int*)d_in[15];

    int N  = in_sizes[0] / D;
    int E_ = in_sizes[1] / EFD;
    int Gc = in_sizes[15];
    const int* srcIdx = eidx;
    const int* dstIdx = eidx + E_;

    float* outHidden = (float*)d_out;
    float* outPooled = outHidden + (size_t)N * D;
    float* outFc     = outPooled + (size_t)Gc * 4 * D;
    float* outLsm    = outFc + (size_t)Gc * 10;

    char* wsp = (char*)d_ws;
    size_t off = 0;
    auto alloc = [&](size_t bytes) -> void* {
        void* p = wsp + off;
        off = (off + bytes + 255) & ~(size_t)255;
        return p;
    };
    int*   cnt2    = (int*)alloc((size_t)2 * N * 4);          // cntS | cntD
    int*   offs2   = (int*)alloc((size_t)2 * (N + 1) * 4);    // offsS | offsD
    int*   bsum2   = (int*)alloc(128 * 4);
    int*   rankS   = (int*)alloc((size_t)E_ * 4);
    int*   rankD   = (int*)alloc((size_t)E_ * 4);
    int*   permInv = (int*)alloc((size_t)E_ * 4);
    u16*   hE      = (u16*)alloc((size_t)E_ * D * 2);         // bf16
    u16*   msg     = (u16*)alloc((size_t)E_ * D * 2);         // bf16
    float* bufA    = (float*)alloc((size_t)N * D * 4);
    float* tmp     = (float*)alloc((size_t)N * D * 4);
    float* statsR3 = (float*)alloc((size_t)3 * NREP * 32 * 4); // one slot per layer

    int* offsS = offs2;
    int* offsD = offs2 + (N + 1);
    int nScan = (N + 1023) / 1024;

    k_zero2<<<(2 * N + 255) / 256, 256, 0, stream>>>(cnt2, 2 * N, statsR3, 3 * NREP * 32);
    k_rank2<<<(E_ + 255) / 256, 256, 0, stream>>>(srcIdx, dstIdx, cnt2, cnt2 + N,
                                                  rankS, rankD, E_);
    k_scanA2<<<2 * nScan, 1024, 0, stream>>>(cnt2, offs2, bsum2, N, nScan);
    k_scanC2<<<2 * nScan, 1024, 0, stream>>>(offs2, bsum2, N, nScan, E_);
    k_place_he<<<(E_ + 255) / 256, 256, 0, stream>>>(srcIdx, dstIdx, rankS, rankD,
                                                     offsS, offsD, ea, ew1, eb1,
                                                     hE, permInv, E_);

    for (int l = 0; l < 3; l++) {
        const float* hin   = (l == 0) ? x : tmp;   // x or hpre of prev layer
        const float* hroot = (l == 0) ? x : bufA;  // post-BN h for root term
        float* statsCur = statsR3 + (size_t)l * NREP * 32;
        const float* statsPrev = statsR3 + (size_t)(l - 1) * NREP * 32;
        k_Tmsg<<<(N + 15) / 16, 256, 0, stream>>>(
            hin, (l == 0) ? nullptr : statsPrev,
            (l == 0) ? nullptr : gam + (size_t)(l - 1) * 16,
            (l == 0) ? nullptr : bet + (size_t)(l - 1) * 16,
            bufA, ew2, eb2, hE, offsS, permInv, msg, N, (l == 0) ? 0 : 1);
        k_agg<<<(N + 15) / 16, 256, 0, stream>>>(hroot, msg, offsD,
                                                 root + (size_t)l * 256, cb + (size_t)l * 16,
                                                 tmp, statsCur, N);
    }

    k_readout<<<Gc, 512, 0, stream>>>(tmp, statsR3 + (size_t)2 * NREP * 32,
                                      gam + 32, bet + 32, lens, f1w, f1b, f2w, f2b,
                                      outHidden, outPooled, outFc, outLsm, Gc, N);
}

// Round 12
// 287.188 us; speedup vs baseline: 7.3260x; 1.0149x over previous
//
#include <hip/hip_runtime.h>

#define D 16
#define EFD 8
#define NREP 64       // BN-stats replica buffers (breaks atomic same-line contention)
#define TSTRIDE 272   // Tt row: 256 T values + 16 bias; 272%32==16 -> benign aliasing

typedef unsigned short u16;
typedef unsigned int u32;

__device__ __forceinline__ u16 f2bf(float x) {          // round-to-nearest-even
    u32 u = __float_as_uint(x);
    u += 0x7fffu + ((u >> 16) & 1u);
    return (u16)(u >> 16);
}
__device__ __forceinline__ void unpack8(uint4 u, float* f) {
    f[0] = __uint_as_float(u.x << 16); f[1] = __uint_as_float(u.x & 0xffff0000u);
    f[2] = __uint_as_float(u.y << 16); f[3] = __uint_as_float(u.y & 0xffff0000u);
    f[4] = __uint_as_float(u.z << 16); f[5] = __uint_as_float(u.z & 0xffff0000u);
    f[6] = __uint_as_float(u.w << 16); f[7] = __uint_as_float(u.w & 0xffff0000u);
}

// ---------------- zero scratch ----------------

__global__ void k_zero2(int* a, int na, float* b, int nb) {
    int i = blockIdx.x * 256 + threadIdx.x;
    if (i < na) a[i] = 0;
    if (i < nb) b[i] = 0.f;
}

// ---------------- rank: one atomic per edge per side ----------------

__global__ void k_rank2(const int* __restrict__ src, const int* __restrict__ dst,
                        int* __restrict__ cntS, int* __restrict__ cntD,
                        int* __restrict__ rankS, int* __restrict__ rankD, int E_) {
    int e = blockIdx.x * 256 + threadIdx.x;
    if (e < E_) {
        rankS[e] = atomicAdd(&cntS[src[e]], 1);
        rankD[e] = atomicAdd(&cntD[dst[e]], 1);
    }
}

// ---------------- scans over cntS|cntD ----------------

__global__ void k_scanA2(const int* __restrict__ cnt2, int* __restrict__ offs2,
                         int* __restrict__ bsum2, int n, int nScan) {
    __shared__ int s[1024];
    int half = blockIdx.x / nScan;
    int blk  = blockIdx.x % nScan;
    const int* c = cnt2 + (size_t)half * n;
    int* of = offs2 + (size_t)half * (n + 1);
    int* bs = bsum2 + half * 64;
    int i = blk * 1024 + threadIdx.x;
    int v = (i < n) ? c[i] : 0;
    s[threadIdx.x] = v;
    __syncthreads();
    for (int d = 1; d < 1024; d <<= 1) {
        int t = (threadIdx.x >= d) ? s[threadIdx.x - d] : 0;
        __syncthreads();
        s[threadIdx.x] += t;
        __syncthreads();
    }
    int incl = s[threadIdx.x];
    if (i < n) of[i] = incl - v;
    if (threadIdx.x == 1023) bs[blk] = incl;
}

__global__ void k_scanC2(int* __restrict__ offs2, const int* __restrict__ bsum2,
                         int n, int nScan, int total) {
    __shared__ int s[64];
    int half = blockIdx.x / nScan;
    int blk  = blockIdx.x % nScan;
    int* of = offs2 + (size_t)half * (n + 1);
    const int* bs = bsum2 + half * 64;
    if (threadIdx.x < 64) s[threadIdx.x] = (threadIdx.x < nScan) ? bs[threadIdx.x] : 0;
    __syncthreads();
    if (threadIdx.x < 64) {
        for (int d = 1; d < 64; d <<= 1) {
            int t = (threadIdx.x >= d) ? s[threadIdx.x - d] : 0;
            __syncthreads();
            s[threadIdx.x] += t;
            __syncthreads();
        }
    } else {
        for (int d = 1; d < 64; d <<= 1) { __syncthreads(); __syncthreads(); }
    }
    int base = (blk == 0) ? 0 : s[blk - 1];
    int i = blk * 1024 + threadIdx.x;
    if (i < n) of[i] += base;
    else if (i == n) of[n] = total;
}

// ---------------- fused place + edge-MLP + permInv (hE bf16) ----------------

__global__ void k_place_he(const int* __restrict__ src, const int* __restrict__ dst,
                           const int* __restrict__ rankS, const int* __restrict__ rankD,
                           const int* __restrict__ offsS, const int* __restrict__ offsD,
                           const float* __restrict__ ea, const float* __restrict__ w1,
                           const float* __restrict__ b1,
                           u16* __restrict__ hE, int* __restrict__ permInv, int E_) {
    __shared__ float w1s[EFD * D];
    __shared__ float b1s[D];
    if (threadIdx.x < EFD * D) w1s[threadIdx.x] = w1[threadIdx.x];
    if (threadIdx.x < D) b1s[threadIdx.x] = b1[threadIdx.x];
    __syncthreads();
    int e = blockIdx.x * 256 + threadIdx.x;
    if (e >= E_) return;
    int p = offsS[src[e]] + rankS[e];
    int q = offsD[dst[e]] + rankD[e];
    permInv[p] = q;
    const float4* a4 = (const float4*)(ea + (size_t)e * EFD);
    float4 x0 = a4[0], x1 = a4[1];
    u32 pk[8];
#pragma unroll
    for (int v = 0; v < 8; v++) {
        float o0, o1;
#pragma unroll
        for (int h = 0; h < 2; h++) {
            int o = 2 * v + h;
            float u0 = x0.x * w1s[0 * D + o] + x0.y * w1s[1 * D + o]
                     + x0.z * w1s[2 * D + o] + x0.w * w1s[3 * D + o];
            float u1 = x1.x * w1s[4 * D + o] + x1.y * w1s[5 * D + o]
                     + x1.z * w1s[6 * D + o] + x1.w * w1s[7 * D + o];
            float t = tanhf(b1s[o] + u0 + u1);
            if (h == 0) o0 = t; else o1 = t;
        }
        pk[v] = (u32)f2bf(o0) | ((u32)f2bf(o1) << 16);
    }
    uint4* h8 = (uint4*)(hE + (size_t)p * D);
    h8[0] = make_uint4(pk[0], pk[1], pk[2], pk[3]);
    h8[1] = make_uint4(pk[4], pk[5], pk[6], pk[7]);
}

// ---------------- per-layer FUSED: BN + T-tile + messages (LDS-staged bulk hE) ----------------
// Group = 16 lanes of one node. hE rows are contiguous (src-sorted): 8 rows bulk-loaded per
// coalesced uint4 wave-inst, double-buffered through wave-private padded LDS (group stride
// 17 uint4 -> 4 groups on disjoint bank sets). permInv fetched 8-at-a-time + __shfl bcast.

#define SBSTRIDE 17   // uint4 stride per group buffer (bank-conflict padding)

__global__ void k_Tmsg(const float* __restrict__ hin, const float* __restrict__ statsPrev,
                       const float* __restrict__ gamma, const float* __restrict__ beta,
                       float* __restrict__ hout, const float* __restrict__ w2,
                       const float* __restrict__ b2, const u16* __restrict__ hE,
                       const int* __restrict__ offsS, const int* __restrict__ permInv,
                       u16* __restrict__ msg, int n, int useBN) {
    __shared__ float hs[16 * D];
    __shared__ float Tt[16 * TSTRIDE];
    __shared__ float sstats[32];
    __shared__ uint4 sbuf[4 * 2 * 4 * SBSTRIDE + 4];   // [wave][buf][group][17]
    int tid = threadIdx.x;
    int j = tid >> 4, o = tid & 15;
    int w = tid >> 6, jj = j & 3;
    int base = blockIdx.x * 16;
    int node = base + j;
    float fn = (float)n;
    int p0 = 0, p1 = 0;
    if (node < n) { p0 = offsS[node]; p1 = offsS[node + 1]; }
    int deg = p1 - p0;
    int nCh = (deg + 7) >> 3;
    uint4* buf0 = &sbuf[((w * 2 + 0) * 4 + jj) * SBSTRIDE];
    uint4* buf1 = &sbuf[((w * 2 + 1) * 4 + jj) * SBSTRIDE];

    // chunk-0 prefetch (global latency hides under the T phase)
    uint4 regH = make_uint4(0, 0, 0, 0);
    int regQ = 0;
    if (deg > 0) {
        int pr = p0 + (o >> 1);
        int pc = (pr < p1) ? pr : p1 - 1;
        regH = ((const uint4*)(hE + (size_t)pc * D))[o & 1];
        if (o < 8) {
            int pq = p0 + o;
            regQ = permInv[(pq < p1) ? pq : p1 - 1];
        }
    }

    // per-thread weight columns in registers
    float w16[16], b16[16];
#pragma unroll
    for (int i = 0; i < 16; i++) w16[i] = w2[j * 256 + i * 16 + o];
#pragma unroll
    for (int i = 0; i < 16; i++) b16[i] = b2[i * 16 + o];
    if (useBN && tid < 32) {
        float a = 0.f;
#pragma unroll 8
        for (int r = 0; r < NREP; r++) a += statsPrev[r * 32 + tid];
        sstats[tid] = a;
    }
    __syncthreads();
    {   // stage h rows (apply BN+tanh of previous layer if needed)
        float hv = 0.f;
        if (node < n) {
            float xin = hin[(size_t)node * D + o];
            if (useBN) {
                float mu = sstats[o] / fn;
                float var = sstats[16 + o] / fn - mu * mu;
                hv = tanhf((xin - mu) * rsqrtf(var + 1e-5f) * gamma[o] + beta[o]);
                hout[(size_t)node * D + o] = hv;
            } else {
                hv = xin;
            }
        }
        hs[tid] = hv;
    }
    __syncthreads();
    {   // T-tile: broadcast b128 reads of hs + register FMAs (4-way trees)
        const float4* hs4 = (const float4*)hs;
#pragma unroll
        for (int nb = 0; nb < 16; nb++) {
            float4 h0 = hs4[nb * 4 + 0], h1 = hs4[nb * 4 + 1];
            float4 h2 = hs4[nb * 4 + 2], h3 = hs4[nb * 4 + 3];
            float q0 = h0.x * w16[0]  + h0.y * w16[1]  + h0.z * w16[2]  + h0.w * w16[3];
            float q1 = h1.x * w16[4]  + h1.y * w16[5]  + h1.z * w16[6]  + h1.w * w16[7];
            float q2 = h2.x * w16[8]  + h2.y * w16[9]  + h2.z * w16[10] + h2.w * w16[11];
            float q3 = h3.x * w16[12] + h3.y * w16[13] + h3.z * w16[14] + h3.w * w16[15];
            Tt[nb * TSTRIDE + tid] = (q0 + q1) + (q2 + q3);
        }
        float4 h0 = hs4[j * 4 + 0], h1 = hs4[j * 4 + 1];
        float4 h2 = hs4[j * 4 + 2], h3 = hs4[j * 4 + 3];
        float q0 = h0.x * b16[0]  + h0.y * b16[1]  + h0.z * b16[2]  + h0.w * b16[3];
        float q1 = h1.x * b16[4]  + h1.y * b16[5]  + h1.z * b16[6]  + h1.w * b16[7];
        float q2 = h2.x * b16[8]  + h2.y * b16[9]  + h2.z * b16[10] + h2.w * b16[11];
        float q3 = h3.x * b16[12] + h3.y * b16[13] + h3.z * b16[14] + h3.w * b16[15];
        Tt[j * TSTRIDE + 256 + o] = (q0 + q1) + (q2 + q3);
    }
    __syncthreads();
    if (node < n && deg > 0) {   // message phase: chunked LDS-staged degree loop
        float tr[16];
#pragma unroll
        for (int j2 = 0; j2 < 16; j2++) tr[j2] = Tt[j * TSTRIDE + j2 * 16 + o];
        float tb = Tt[j * TSTRIDE + 256 + o];
        buf0[o] = regH;                      // stage chunk 0
        for (int c = 0; c < nCh; c++) {
            uint4* cur = (c & 1) ? buf1 : buf0;
            uint4* nxt = (c & 1) ? buf0 : buf1;
            uint4 nH; int nQ = 0;
            if (c + 1 < nCh) {               // issue next chunk's global loads now
                int pr = p0 + (c + 1) * 8 + (o >> 1);
                int pc = (pr < p1) ? pr : p1 - 1;
                nH = ((const uint4*)(hE + (size_t)pc * D))[o & 1];
                if (o < 8) {
                    int pq = p0 + (c + 1) * 8 + o;
                    nQ = permInv[(pq < p1) ? pq : p1 - 1];
                }
            }
            int eMax = deg - c * 8;
            if (eMax > 8) eMax = 8;
            for (int i = 0; i < eMax; i++) {
                uint4 r0 = cur[2 * i], r1 = cur[2 * i + 1];   // broadcast reads
                int qe = __shfl(regQ, jj * 16 + i);
                float e[16];
                unpack8(r0, e); unpack8(r1, e + 8);
                float s0 = e[0]  * tr[0]  + e[1]  * tr[1]  + e[2]  * tr[2]  + e[3]  * tr[3];
                float s1 = e[4]  * tr[4]  + e[5]  * tr[5]  + e[6]  * tr[6]  + e[7]  * tr[7];
                float s2 = e[8]  * tr[8]  + e[9]  * tr[9]  + e[10] * tr[10] + e[11] * tr[11];
                float s3 = e[12] * tr[12] + e[13] * tr[13] + e[14] * tr[14] + e[15] * tr[15];
                msg[(size_t)qe * D + o] = f2bf(tb + ((s0 + s1) + (s2 + s3)));
            }
            if (c + 1 < nCh) {
                nxt[o] = nH;                 // stage next chunk
                regQ = nQ;
            }
        }
    }
}

// ---------------- per-layer: dst aggregation (sequential bf16 msg read) + root + BN stats ----------------

__global__ void k_agg(const float* __restrict__ h, const u16* __restrict__ msg,
                      const int* __restrict__ offsD, const float* __restrict__ root_l,
                      const float* __restrict__ cbias, float* __restrict__ hpre,
                      float* __restrict__ statsR, int n) {
    __shared__ float rootS[D * D];
    __shared__ float red[256], red2[256];
    if (threadIdx.x < D * D) rootS[threadIdx.x] = root_l[threadIdx.x];
    __syncthreads();
    int slot = threadIdx.x >> 4, o = threadIdx.x & 15;
    int node = blockIdx.x * 16 + slot;
    float acc = 0.f;
    if (node < n) {
        int p0 = offsD[node], p1 = offsD[node + 1];
        float sum = 0.f;
        int p = p0;
        for (; p + 8 <= p1; p += 8) {           // 8 independent loads in flight
            float a0 = __uint_as_float((u32)msg[(size_t)(p + 0) * D + o] << 16);
            float a1 = __uint_as_float((u32)msg[(size_t)(p + 1) * D + o] << 16);
            float a2 = __uint_as_float((u32)msg[(size_t)(p + 2) * D + o] << 16);
            float a3 = __uint_as_float((u32)msg[(size_t)(p + 3) * D + o] << 16);
            float a4 = __uint_as_float((u32)msg[(size_t)(p + 4) * D + o] << 16);
            float a5 = __uint_as_float((u32)msg[(size_t)(p + 5) * D + o] << 16);
            float a6 = __uint_as_float((u32)msg[(size_t)(p + 6) * D + o] << 16);
            float a7 = __uint_as_float((u32)msg[(size_t)(p + 7) * D + o] << 16);
            sum += ((a0 + a1) + (a2 + a3)) + ((a4 + a5) + (a6 + a7));
        }
        for (; p < p1; p++) sum += __uint_as_float((u32)msg[(size_t)p * D + o] << 16);
        float deg = (float)((p1 - p0) > 1 ? (p1 - p0) : 1);
        const float* hr = h + (size_t)node * D;
        float r0 = hr[0]  * rootS[0 * D + o]  + hr[1]  * rootS[1 * D + o]
                 + hr[2]  * rootS[2 * D + o]  + hr[3]  * rootS[3 * D + o];
        float r1 = hr[4]  * rootS[4 * D + o]  + hr[5]  * rootS[5 * D + o]
                 + hr[6]  * rootS[6 * D + o]  + hr[7]  * rootS[7 * D + o];
        float r2 = hr[8]  * rootS[8 * D + o]  + hr[9]  * rootS[9 * D + o]
                 + hr[10] * rootS[10 * D + o] + hr[11] * rootS[11 * D + o];
        float r3 = hr[12] * rootS[12 * D + o] + hr[13] * rootS[13 * D + o]
                 + hr[14] * rootS[14 * D + o] + hr[15] * rootS[15 * D + o];
        acc = sum / deg + cbias[o] + ((r0 + r1) + (r2 + r3));
        hpre[(size_t)node * D + o] = acc;
    }
    red[threadIdx.x] = acc;
    red2[threadIdx.x] = acc * acc;
    __syncthreads();
    for (int off = 128; off >= 16; off >>= 1) {
        if (threadIdx.x < off) {
            red[threadIdx.x] += red[threadIdx.x + off];
            red2[threadIdx.x] += red2[threadIdx.x + off];
        }
        __syncthreads();
    }
    if (threadIdx.x < 32) {
        float v = (threadIdx.x < 16) ? red[threadIdx.x] : red2[threadIdx.x - 16];
        atomicAdd(&statsR[(blockIdx.x & (NREP - 1)) * 32 + threadIdx.x], v);
    }
}

// ---------------- fused readout ----------------

__global__ void k_readout(const float* __restrict__ hpre, const float* __restrict__ statsR,
                          const float* __restrict__ gamma, const float* __restrict__ beta,
                          const int* __restrict__ lengths,
                          const float* __restrict__ w1, const float* __restrict__ b1,
                          const float* __restrict__ w2, const float* __restrict__ b2,
                          float* __restrict__ outHidden, float* __restrict__ outPooled,
                          float* __restrict__ fcOut, float* __restrict__ lsmOut,
                          int Gc, int n) {
    __shared__ int sl[512];
    __shared__ float sstats[32];
    int tid = threadIdx.x;
    int g = blockIdx.x;
    if (tid < 32) {
        float a = 0.f;
#pragma unroll 8
        for (int r = 0; r < NREP; r++) a += statsR[r * 32 + tid];
        sstats[tid] = a;
    }
    int v = (tid < Gc) ? lengths[tid] : 0;
    sl[tid] = v;
    __syncthreads();
    for (int d = 1; d < 512; d <<= 1) {
        int t = (tid >= d) ? sl[tid - d] : 0;
        __syncthreads();
        sl[tid] += t;
        __syncthreads();
    }
    int n1 = sl[g];
    int n0 = n1 - lengths[g];
    float fn = (float)n;
    int slot = tid >> 4, o = tid & 15;
    float mu = sstats[o] / fn;
    float var = sstats[16 + o] / fn - mu * mu;
    float rstd = rsqrtf(var + 1e-5f);
    float gm = gamma[o], bt = beta[o];
    float s = 0.f, mx = -3.402823466e38f, mn = 3.402823466e38f;
    for (int nd = n0 + slot; nd < n1; nd += 32) {
        float xin = hpre[(size_t)nd * D + o];
        float x = tanhf((xin - mu) * rstd * gm + bt);
        outHidden[(size_t)nd * D + o] = x;
        s += x;
        mx = fmaxf(mx, x);
        mn = fminf(mn, x);
    }
    __shared__ float rs[512], rmx[512], rmn[512];
    rs[tid] = s; rmx[tid] = mx; rmn[tid] = mn;
    __syncthreads();
    for (int off = 256; off >= 16; off >>= 1) {
        if (tid < off) {
            rs[tid] += rs[tid + off];
            rmx[tid] = fmaxf(rmx[tid], rmx[tid + off]);
            rmn[tid] = fminf(rmn[tid], rmn[tid + off]);
        }
        __syncthreads();
    }
    __shared__ float p64[64], t16[16], f10[10];
    __shared__ float mred, lred;
    if (tid < 16) {
        float cnt = fmaxf((float)(n1 - n0), 1.f);
        float sum = rs[tid];
        float* row = outPooled + (size_t)g * 64;
        float mean = sum / cnt;
        p64[tid] = mean;          row[tid] = mean;
        p64[16 + tid] = rmx[tid]; row[16 + tid] = rmx[tid];
        p64[32 + tid] = rmn[tid]; row[32 + tid] = rmn[tid];
        p64[48 + tid] = sum;      row[48 + tid] = sum;
    }
    __syncthreads();
    if (tid < 16) {
        float a = b1[tid];
        for (int k = 0; k < 64; k++) a += p64[k] * w1[k * 16 + tid];
        t16[tid] = tanhf(a);
    }
    __syncthreads();
    if (tid < 10) {
        float a = b2[tid];
        for (int oo = 0; oo < 16; oo++) a += t16[oo] * w2[oo * 10 + tid];
        f10[tid] = a;
        fcOut[(size_t)g * 10 + tid] = a;
    }
    __syncthreads();
    if (tid == 0) {
        float m = f10[0];
        for (int c = 1; c < 10; c++) m = fmaxf(m, f10[c]);
        float se = 0.f;
        for (int c = 0; c < 10; c++) se += expf(f10[c] - m);
        mred = m;
        lred = logf(se);
    }
    __syncthreads();
    if (tid < 10)
        lsmOut[(size_t)g * 10 + tid] = f10[tid] - mred - lred;
}

// ---------------- host ----------------

extern "C" void kernel_launch(void* const* d_in, const int* in_sizes, int n_in,
                              void* d_out, int out_size, void* d_ws, size_t ws_size,
                              hipStream_t stream) {
    const float* x    = (const float*)d_in[0];
    const float* ea   = (const float*)d_in[1];
    const float* ew1  = (const float*)d_in[2];
    const float* eb1  = (const float*)d_in[3];
    const float* ew2  = (const float*)d_in[4];
    const float* eb2  = (const float*)d_in[5];
    const float* root = (const float*)d_in[6];
    const float* cb   = (const float*)d_in[7];
    const float* gam  = (const float*)d_in[8];
    const float* bet  = (const float*)d_in[9];
    const float* f1w  = (const float*)d_in[10];
    const float* f1b  = (const float*)d_in[11];
    const float* f2w  = (const float*)d_in[12];
    const float* f2b  = (const float*)d_in[13];
    const int* eidx   = (const int*)d_in[14];
    const int* lens   = (const int*)d_in[15];

    int N  = in_sizes[0] / D;
    int E_ = in_sizes[1] / EFD;
    int Gc = in_sizes[15];
    const int* srcIdx = eidx;
    const int* dstIdx = eidx + E_;

    float* outHidden = (float*)d_out;
    float* outPooled = outHidden + (size_t)N * D;
    float* outFc     = outPooled + (size_t)Gc * 4 * D;
    float* outLsm    = outFc + (size_t)Gc * 10;

    char* wsp = (char*)d_ws;
    size_t off = 0;
    auto alloc = [&](size_t bytes) -> void* {
        void* p = wsp + off;
        off = (off + bytes + 255) & ~(size_t)255;
        return p;
    };
    int*   cnt2    = (int*)alloc((size_t)2 * N * 4);
    int*   offs2   = (int*)alloc((size_t)2 * (N + 1) * 4);
    int*   bsum2   = (int*)alloc(128 * 4);
    int*   rankS   = (int*)alloc((size_t)E_ * 4);
    int*   rankD   = (int*)alloc((size_t)E_ * 4);
    int*   permInv = (int*)alloc((size_t)E_ * 4);
    u16*   hE      = (u16*)alloc((size_t)E_ * D * 2);
    u16*   msg     = (u16*)alloc((size_t)E_ * D * 2);
    float* bufA    = (float*)alloc((size_t)N * D * 4);
    float* tmp     = (float*)alloc((size_t)N * D * 4);
    float* statsR3 = (float*)alloc((size_t)3 * NREP * 32 * 4);

    int* offsS = offs2;
    int* offsD = offs2 + (N + 1);
    int nScan = (N + 1023) / 1024;

    k_zero2<<<(2 * N + 255) / 256, 256, 0, stream>>>(cnt2, 2 * N, statsR3, 3 * NREP * 32);
    k_rank2<<<(E_ + 255) / 256, 256, 0, stream>>>(srcIdx, dstIdx, cnt2, cnt2 + N,
                                                  rankS, rankD, E_);
    k_scanA2<<<2 * nScan, 1024, 0, stream>>>(cnt2, offs2, bsum2, N, nScan);
    k_scanC2<<<2 * nScan, 1024, 0, stream>>>(offs2, bsum2, N, nScan, E_);
    k_place_he<<<(E_ + 255) / 256, 256, 0, stream>>>(srcIdx, dstIdx, rankS, rankD,
                                                     offsS, offsD, ea, ew1, eb1,
                                                     hE, permInv, E_);

    for (int l = 0; l < 3; l++) {
        const float* hin   = (l == 0) ? x : tmp;
        const float* hroot = (l == 0) ? x : bufA;
        float* statsCur = statsR3 + (size_t)l * NREP * 32;
        const float* statsPrev = statsR3 + (size_t)(l - 1) * NREP * 32;
        k_Tmsg<<<(N + 15) / 16, 256, 0, stream>>>(
            hin, (l == 0) ? nullptr : statsPrev,
            (l == 0) ? nullptr : gam + (size_t)(l - 1) * 16,
            (l == 0) ? nullptr : bet + (size_t)(l - 1) * 16,
            bufA, ew2, eb2, hE, offsS, permInv, msg, N, (l == 0) ? 0 : 1);
        k_agg<<<(N + 15) / 16, 256, 0, stream>>>(hroot, msg, offsD,
                                                 root + (size_t)l * 256, cb + (size_t)l * 16,
                                                 tmp, statsCur, N);
    }

    k_readout<<<Gc, 512, 0, stream>>>(tmp, statsR3 + (size_t)2 * NREP * 32,
                                      gam + 32, bet + 32, lens, f1w, f1b, f2w, f2b,
                                      outHidden, outPooled, outFc, outLsm, Gc, N);
}